// Round 8
// baseline (407.807 us; speedup 1.0000x reference)
//
#include <hip/hip_runtime.h>
#include <hip/hip_bf16.h>
#include <math.h>

// Problem constants
#define B 16
#define S 4096
#define D 64
#define NH 8
#define NBUCK 64          // buckets per hash
#define CHUNKS 512        // chunks per batch (NH * NBUCK)
#define BS 64             // bucket/chunk size

#define GAP_MFMA 0.12f    // flag threshold: covers bf16-R rounding err (5sigma~0.06)

typedef __attribute__((ext_vector_type(8))) short s8_t;   // 8 bf16 (4 VGPRs)
typedef __attribute__((ext_vector_type(4))) float f4_t;   // MFMA C/D

__device__ inline unsigned short bf16_rne(float x) {
    unsigned int u = __float_as_uint(x);
    u += 0x7fffu + ((u >> 16) & 1u);
    return (unsigned short)(u >> 16);
}
__device__ inline unsigned int pack_bf16_pair(float x0, float x1) {
    return (unsigned int)bf16_rne(x0) | ((unsigned int)bf16_rne(x1) << 16);
}
__device__ inline void split_bf16(float x, unsigned short& h, unsigned short& l) {
    h = bf16_rne(x);
    float hf = __uint_as_float(((unsigned int)h) << 16);
    l = bf16_rne(x - hf);
}
// truncation-pack two f32 into (bf16(x0) | bf16(x1)<<16): one v_perm_b32
__device__ inline unsigned int pack_trunc(float x0, float x1) {
    return __builtin_amdgcn_perm(__float_as_uint(x1), __float_as_uint(x0),
                                 0x07060302u);
}
__device__ inline unsigned short bf16_trunc(float x) {
    return (unsigned short)(__float_as_uint(x) >> 16);
}

// ---------------------------------------------------------------------------
// Kernel 1: MFMA hash. rotated = qk @ rot as GEMM: A[m=256 outputs(8h x 32i)]
// [k=64], B[k=64][n=tokens] (qk split hi/lo -> 2 MFMAs, R plain bf16 RNE).
// C: col=lane&15 -> token, row=quad*4+reg -> output. Per odd m-tile, finalize
// per-h top-2 (signed candidates [v,-v]) with quad butterfly merge; tokens
// with gap < GAP_MFMA flagged for exact f64 fixup (ties -> gap 0 -> flagged).
// Block: 256 thr, 128 tokens, all 8 h. Grid: B * 32. LDS 72 KB -> 2 blk/CU.
// ---------------------------------------------------------------------------
#define HA_OFF 0          // A (R) : 256 rows x 144 B
#define HQH_OFF 36864     // Q hi  : 128 rows x 144 B
#define HQL_OFF 55296     // Q lo  : 128 rows x 144 B
#define HLDS_TOT 73728
#define HSTR 144          // row stride bytes (64 bf16 + 8 pad)

__global__ __launch_bounds__(256, 2) void hash_kernel(
    const float* __restrict__ qk, const float* __restrict__ rot,
    float* __restrict__ out_buckets, int* __restrict__ bucket_ws,
    int* __restrict__ flag_cnt, int* __restrict__ flag_list)
{
    __shared__ char lds[HLDS_TOT];
    int tid = threadIdx.x;
    int b    = blockIdx.x >> 5;
    int tile = blockIdx.x & 31;
    int token0 = tile * 128;

    // ---- stage A = R_all: A[m][f] = rot[f*256 + m], bf16 RNE ----
    {
        char* arow = lds + HA_OFF + tid * HSTR;
        #pragma unroll 4
        for (int f = 0; f < 64; f += 2) {
            float r0 = rot[(size_t)f * 256 + tid];
            float r1 = rot[(size_t)(f + 1) * 256 + tid];
            *(unsigned int*)(arow + f * 2) = pack_bf16_pair(r0, r1);
        }
    }
    // ---- stage B = qk tile, split hi/lo ----
    {
        int r = tid >> 1, half = tid & 1;
        int tok = token0 + r;
        const float4* qs = (const float4*)(qk + ((size_t)b * S + tok) * D) + half * 8;
        float xq[32];
        #pragma unroll
        for (int e4 = 0; e4 < 8; ++e4) {
            float4 a = qs[e4];
            xq[e4*4+0]=a.x; xq[e4*4+1]=a.y; xq[e4*4+2]=a.z; xq[e4*4+3]=a.w;
        }
        unsigned int ph[16], pl[16];
        #pragma unroll
        for (int e = 0; e < 16; ++e) {
            unsigned short h0,l0,h1,l1;
            split_bf16(xq[2*e],   h0, l0);
            split_bf16(xq[2*e+1], h1, l1);
            ph[e] = (unsigned int)h0 | ((unsigned int)h1 << 16);
            pl[e] = (unsigned int)l0 | ((unsigned int)l1 << 16);
        }
        char* qh = lds + HQH_OFF + r * HSTR + half * 64;
        char* ql = lds + HQL_OFF + r * HSTR + half * 64;
        #pragma unroll
        for (int e4 = 0; e4 < 4; ++e4) {
            *(uint4*)(qh + e4*16) = make_uint4(ph[e4*4], ph[e4*4+1], ph[e4*4+2], ph[e4*4+3]);
            *(uint4*)(ql + e4*16) = make_uint4(pl[e4*4], pl[e4*4+1], pl[e4*4+2], pl[e4*4+3]);
        }
    }
    __syncthreads();

    int wv   = tid >> 6;
    int lane = tid & 63;
    int quad = lane >> 4;
    int cc   = lane & 15;

    for (int nt = 0; nt < 2; ++nt) {
        int ntg = wv * 2 + nt;            // 0..7 (16-token groups)
        const char* qrh = lds + HQH_OFF + (ntg * 16 + cc) * HSTR + quad * 16;
        const char* qrl = lds + HQL_OFF + (ntg * 16 + cc) * HSTR + quad * 16;
        s8_t bh0 = *(const s8_t*)(qrh);
        s8_t bh1 = *(const s8_t*)(qrh + 64);
        s8_t bl0 = *(const s8_t*)(qrl);
        s8_t bl1 = *(const s8_t*)(qrl + 64);

        float v1 = -3e38f, v2 = -3e38f;
        int i1 = 0;

        for (int mt = 0; mt < 16; ++mt) {
            const char* arow = lds + HA_OFF + (mt * 16 + cc) * HSTR + quad * 16;
            s8_t a0 = *(const s8_t*)(arow);
            s8_t a1 = *(const s8_t*)(arow + 64);
            f4_t acc = (f4_t){0.f, 0.f, 0.f, 0.f};
            acc = __builtin_amdgcn_mfma_f32_16x16x32_bf16(a0, bh0, acc, 0, 0, 0);
            acc = __builtin_amdgcn_mfma_f32_16x16x32_bf16(a1, bh1, acc, 0, 0, 0);
            acc = __builtin_amdgcn_mfma_f32_16x16x32_bf16(a0, bl0, acc, 0, 0, 0);
            acc = __builtin_amdgcn_mfma_f32_16x16x32_bf16(a1, bl1, acc, 0, 0, 0);

            if ((mt & 1) == 0) { v1 = -3e38f; v2 = -3e38f; i1 = 0; }
            int ibase = ((mt & 1) << 4) + (quad << 2);
            #pragma unroll
            for (int r = 0; r < 4; ++r) {
                float vp = acc[r];
                int ip = ibase + r;
                v2 = fmaxf(v2, fminf(vp, v1));
                if (vp > v1) { v1 = vp; i1 = ip; }
                float vn = -vp;
                v2 = fmaxf(v2, fminf(vn, v1));
                if (vn > v1) { v1 = vn; i1 = ip + 32; }
            }

            if (mt & 1) {
                // butterfly merge across the 4 quads (lane bits 4,5)
                #pragma unroll
                for (int off = 16; off <= 32; off <<= 1) {
                    float ov1 = __shfl_xor(v1, off, 64);
                    float ov2 = __shfl_xor(v2, off, 64);
                    int   oi1 = __shfl_xor(i1, off, 64);
                    float nv2 = fmaxf(fmaxf(v2, ov2), fminf(v1, ov1));
                    if (ov1 > v1) { v1 = ov1; i1 = oi1; }
                    v2 = nv2;
                }
                if (quad == 0) {
                    int h = mt >> 1;
                    int tok = token0 + ntg * 16 + cc;
                    size_t idx = (size_t)(b * NH + h) * S + tok;
                    bucket_ws[idx] = i1;
                    out_buckets[idx] = (float)(i1 + h * NBUCK);
                    if (v1 - v2 < GAP_MFMA) {
                        int slot = atomicAdd(flag_cnt, 1);
                        flag_list[slot] = (int)idx;
                    }
                }
            }
        }
    }
}

// ---------------------------------------------------------------------------
// Kernel 1b: exact f64 recompute for flagged (ambiguous) tokens.
// Decision-equivalent to a full-f64 hash (first-occurrence ties).
// ---------------------------------------------------------------------------
__global__ __launch_bounds__(256) void hash_fixup_kernel(
    const float* __restrict__ qk, const float* __restrict__ rot,
    const int* __restrict__ flag_cnt, const int* __restrict__ flag_list,
    float* __restrict__ out_buckets, int* __restrict__ bucket_ws)
{
    int n = *flag_cnt;
    for (int g = blockIdx.x * 256 + threadIdx.x; g < n; g += gridDim.x * 256) {
        int gid = flag_list[g];
        int bh = gid >> 12, t = gid & (S - 1);
        int b = bh >> 3, h = bh & 7;
        const float* row = qk + ((size_t)b * S + t) * D;

        double acc[32];
        #pragma unroll
        for (int i = 0; i < 32; ++i) acc[i] = 0.0;
        for (int f = 0; f < 64; ++f) {
            double x = (double)row[f];
            const float* rr = rot + f * (NH * 32) + h * 32;
            #pragma unroll
            for (int i = 0; i < 32; ++i)
                acc[i] = __fma_rn(x, (double)rr[i], acc[i]);
        }
        double best = acc[0]; int bi = 0;
        double worst = acc[0]; int wi = 0;
        #pragma unroll
        for (int i = 1; i < 32; ++i) {
            if (acc[i] > best)  { best = acc[i]; bi = i; }
            if (acc[i] < worst) { worst = acc[i]; wi = i; }
        }
        int bucket = (-worst > best) ? (32 + wi) : bi;
        bucket_ws[gid] = bucket;
        out_buckets[gid] = (float)(bucket + h * NBUCK);
    }
}

// ---------------------------------------------------------------------------
// Kernel 2: parallel stable counting sort per (b,h). 256 threads (4 waves).
// ---------------------------------------------------------------------------
__global__ __launch_bounds__(256) void sort_kernel(
    const int* __restrict__ bucket_ws, int* __restrict__ st_ws)
{
    __shared__ int sb[S];
    __shared__ int hist[4][64];
    __shared__ int bpref[64];
    __shared__ int woff[4][64];

    int tid  = threadIdx.x;
    int wv   = tid >> 6;
    int lane = tid & 63;
    int base = blockIdx.x * S;

    hist[wv][lane] = 0;
    __syncthreads();

    int qbase = wv * 1024;
    #pragma unroll
    for (int i = 0; i < 16; ++i) {
        int t = qbase + i * 64 + lane;
        int v = bucket_ws[base + t];
        sb[t] = v;
        atomicAdd(&hist[wv][v], 1);
    }
    __syncthreads();

    if (wv == 0) {
        int total = hist[0][lane] + hist[1][lane] + hist[2][lane] + hist[3][lane];
        int x = total;
        #pragma unroll
        for (int off = 1; off < 64; off <<= 1) {
            int y = __shfl_up(x, off, 64);
            if (lane >= off) x += y;
        }
        bpref[lane] = x - total;
    }
    __syncthreads();
    {
        int o = bpref[lane];
        for (int w2 = 0; w2 < 4; ++w2) {
            if (w2 < wv) o += hist[w2][lane];
        }
        woff[wv][lane] = o;
    }
    __syncthreads();

    for (int g = 0; g < 16; ++g) {
        int t = qbase + g * 64 + lane;
        int v = sb[t];

        unsigned long long m = ~0ULL;
        #pragma unroll
        for (int bit = 0; bit < 6; ++bit) {
            unsigned long long bm = __ballot((v >> bit) & 1);
            m &= ((v >> bit) & 1) ? bm : ~bm;
        }
        unsigned long long below = (lane == 63) ? ~0ULL >> 1
                                 : ((1ULL << lane) - 1ULL);
        int rank = __popcll(m & below);
        int cnt  = __popcll(m);

        int pos = woff[wv][v] + rank;
        st_ws[base + pos] = t;

        if ((m & below) == 0ULL)
            woff[wv][v] += cnt;
        __builtin_amdgcn_s_waitcnt(0);
    }
}

// ---------------------------------------------------------------------------
// Kernel 3: per-chunk attention, plain-bf16 MFMA, truncation-packed converts.
// LDS layout (37888 B -> 4 blocks/CU):
//   K  [128 rows][144 B] @0      (18432)  normalized keys bf16
//                                 -- rows 0..63 overlaid by P[64][144B] post-dots
//   VtP[64 rows][288 B]  @18432  (18432)  V^T packed: dword = keys(2a,2a+1)
//   nrm @36864 (512), tkx @37376 (512)
// ---------------------------------------------------------------------------
#define OFF_VT 18432
#define OFF_NRM 36864
#define OFF_TKX 37376
#define LDS_TOT 37888
#define KSTRB 144     // K/P row stride bytes (72 bf16), 16B-aligned
#define VSTRD 72      // VtP row stride in dwords (288 B)

__global__ __launch_bounds__(256, 4) void attn_kernel(
    const float* __restrict__ qk, const float* __restrict__ v,
    const int* __restrict__ st_ws,
    __hip_bfloat16* __restrict__ o_ws, float* __restrict__ logits_ws)
{
    __shared__ char lds[LDS_TOT];
    float* nrm_s = (float*)(lds + OFF_NRM);
    int*   tkx   = (int*)(lds + OFF_TKX);
    unsigned int* VtP = (unsigned int*)(lds + OFF_VT);

    int tid = threadIdx.x;
    int c = blockIdx.x & (CHUNKS - 1);
    int b = blockIdx.x >> 9;
    int h = c >> 6;
    int sbase = b * (NH * S);

    if (tid < 128) {
        int cc2 = (tid < 64) ? c : ((c + CHUNKS - 1) & (CHUNKS - 1));
        tkx[tid] = st_ws[sbase + cc2 * BS + (tid & 63)];
    }
    __syncthreads();

    // ---- stage K (normalized bf16, row-major) ----
    {
        int r = tid >> 1, half = tid & 1;
        int tok = tkx[r];
        const float4* qs = (const float4*)(qk + ((size_t)b * S + tok) * D) + half * 8;
        float xq[32];
        #pragma unroll
        for (int e4 = 0; e4 < 8; ++e4) {
            float4 a = qs[e4];
            xq[e4*4+0]=a.x; xq[e4*4+1]=a.y; xq[e4*4+2]=a.z; xq[e4*4+3]=a.w;
        }
        float ss = 0.f;
        #pragma unroll
        for (int e = 0; e < 32; ++e) ss += xq[e]*xq[e];
        ss += __shfl_xor(ss, 1);
        float nr = sqrtf(ss);
        float inv = 1.0f / fmaxf(nr, 1e-12f);
        if (!half) nrm_s[r] = nr;

        unsigned int pk[16];
        #pragma unroll
        for (int e = 0; e < 16; ++e)
            pk[e] = pack_trunc(xq[2*e] * inv, xq[2*e+1] * inv);
        char* kb = lds + r * KSTRB + half * 64;
        #pragma unroll
        for (int e4 = 0; e4 < 4; ++e4)
            *(uint4*)(kb + e4*16) = make_uint4(pk[e4*4], pk[e4*4+1], pk[e4*4+2], pk[e4*4+3]);
    }
    // ---- stage V^T packed (dword = 2 consecutive keys) ----
    {
        int a = tid & 63, sub = tid >> 6;     // a = key pair, sub = dim quarter
        int tok0 = tkx[2*a], tok1 = tkx[2*a+1];
        const float4* v0 = (const float4*)(v + ((size_t)b * S + tok0) * D + sub * 16);
        const float4* v1 = (const float4*)(v + ((size_t)b * S + tok1) * D + sub * 16);
        float x0[16], x1[16];
        #pragma unroll
        for (int e4 = 0; e4 < 4; ++e4) {
            float4 p0 = v0[e4], p1 = v1[e4];
            x0[e4*4+0]=p0.x; x0[e4*4+1]=p0.y; x0[e4*4+2]=p0.z; x0[e4*4+3]=p0.w;
            x1[e4*4+0]=p1.x; x1[e4*4+1]=p1.y; x1[e4*4+2]=p1.z; x1[e4*4+3]=p1.w;
        }
        #pragma unroll
        for (int e = 0; e < 16; ++e) {
            int dd = sub * 16 + e;
            VtP[dd * VSTRD + a] = pack_trunc(x0[e], x1[e]);
        }
    }
    __syncthreads();

    int wv   = tid >> 6;
    int lane = tid & 63;
    int quad = lane >> 4;
    int cc   = lane & 15;

    // ---- dots: QK^T via bf16 MFMA ----
    int qrow = wv * 16 + cc;
    f4_t acc[8];
    #pragma unroll
    for (int t = 0; t < 8; ++t) acc[t] = (f4_t){0.f,0.f,0.f,0.f};

    #pragma unroll
    for (int kc = 0; kc < 2; ++kc) {
        int aoff = kc * 64 + quad * 16;
        s8_t av = *(const s8_t*)(lds + qrow * KSTRB + aoff);
        #pragma unroll
        for (int t = 0; t < 8; ++t) {
            s8_t bv = *(const s8_t*)(lds + (t * 16 + cc) * KSTRB + aoff);
            acc[t] = __builtin_amdgcn_mfma_f32_16x16x32_bf16(av, bv, acc[t], 0, 0, 0);
        }
    }

    // ---- scale + self-mask + softmax ----
    int tqi[4];
    float sc[4];
    #pragma unroll
    for (int g = 0; g < 4; ++g) {
        int q = wv * 16 + quad * 4 + g;
        tqi[g] = tkx[q];
        sc[g] = nrm_s[q] * 0.125f;
    }
    int tki[8];
    #pragma unroll
    for (int t = 0; t < 8; ++t) tki[t] = tkx[t * 16 + cc];

    #pragma unroll
    for (int t = 0; t < 8; ++t)
        #pragma unroll
        for (int g = 0; g < 4; ++g) {
            float d = acc[t][g] * sc[g];
            if (tqi[g] == tki[t]) d = -1e5f;
            acc[t][g] = d;
        }

    float mx[4];
    #pragma unroll
    for (int g = 0; g < 4; ++g) {
        float m = acc[0][g];
        #pragma unroll
        for (int t = 1; t < 8; ++t) m = fmaxf(m, acc[t][g]);
        mx[g] = m;
    }
    #pragma unroll
    for (int msk = 1; msk <= 8; msk <<= 1)
        #pragma unroll
        for (int g = 0; g < 4; ++g) mx[g] = fmaxf(mx[g], __shfl_xor(mx[g], msk, 64));

    float sm[4] = {0.f, 0.f, 0.f, 0.f};
    #pragma unroll
    for (int t = 0; t < 8; ++t)
        #pragma unroll
        for (int g = 0; g < 4; ++g) {
            float p = __expf(acc[t][g] - mx[g]);
            acc[t][g] = p;
            sm[g] += p;
        }
    #pragma unroll
    for (int msk = 1; msk <= 8; msk <<= 1)
        #pragma unroll
        for (int g = 0; g < 4; ++g) sm[g] += __shfl_xor(sm[g], msk, 64);

    float pinv[4];
    #pragma unroll
    for (int g = 0; g < 4; ++g) pinv[g] = 1.0f / sm[g];

    if (cc == 0) {
        #pragma unroll
        for (int g = 0; g < 4; ++g)
            logits_ws[sbase + h * S + tqi[g]] = mx[g] + __logf(sm[g]);
    }

    // ---- P -> bf16 into LDS, overlaying K rows 0..63 ----
    __syncthreads();
    #pragma unroll
    for (int t = 0; t < 8; ++t) {
        int key = t * 16 + cc;
        #pragma unroll
        for (int g = 0; g < 4; ++g) {
            int q = wv * 16 + quad * 4 + g;
            *(unsigned short*)(lds + q * KSTRB + key * 2) =
                bf16_trunc(acc[t][g] * pinv[g]);
        }
    }

    // ---- PV via bf16 MFMA (A = own wave's P rows, B = VtP rows) ----
    f4_t oacc[4];
    #pragma unroll
    for (int n = 0; n < 4; ++n) oacc[n] = (f4_t){0.f,0.f,0.f,0.f};

    #pragma unroll
    for (int kc = 0; kc < 4; ++kc) {
        int koff = kc * 64 + quad * 16;   // byte offset: key k at byte 2k
        s8_t pa = *(const s8_t*)(lds + (wv * 16 + cc) * KSTRB + koff);
        #pragma unroll
        for (int n = 0; n < 4; ++n) {
            s8_t bv = *(const s8_t*)((const char*)(VtP + (n * 16 + cc) * VSTRD) + koff);
            oacc[n] = __builtin_amdgcn_mfma_f32_16x16x32_bf16(pa, bv, oacc[n], 0, 0, 0);
        }
    }

    // ---- write O (bf16, truncation) ----
    #pragma unroll
    for (int g = 0; g < 4; ++g) {
        __hip_bfloat16* op = o_ws + ((size_t)(sbase + h * S + tqi[g])) * D;
        #pragma unroll
        for (int n = 0; n < 4; ++n)
            *(unsigned short*)(op + n * 16 + cc) = bf16_trunc(oacc[n][g]);
    }
}

// ---------------------------------------------------------------------------
// Kernel 4: combine hash rounds with softmax(logits) weights. o_ws is bf16.
// ---------------------------------------------------------------------------
__global__ __launch_bounds__(256) void combine_kernel(
    const __hip_bfloat16* __restrict__ o_ws, const float* __restrict__ logits_ws,
    float* __restrict__ out)
{
    int gid = blockIdx.x * 256 + threadIdx.x;
    int token = gid >> 3;          // b*S + t
    int d8 = gid & 7;
    int b = token >> 12;
    int t = token & (S - 1);
    int base = b * (NH * S) + t;

    float l[8];
    #pragma unroll
    for (int hh = 0; hh < 8; ++hh) l[hh] = logits_ws[base + hh * S];
    float m = l[0];
    #pragma unroll
    for (int hh = 1; hh < 8; ++hh) m = fmaxf(m, l[hh]);
    float w[8]; float ssum = 0.f;
    #pragma unroll
    for (int hh = 0; hh < 8; ++hh) { w[hh] = __expf(l[hh] - m); ssum += w[hh]; }
    float inv = 1.0f / ssum;

    float accv[8] = {0,0,0,0,0,0,0,0};
    #pragma unroll
    for (int hh = 0; hh < 8; ++hh) {
        uint4 pk = *(const uint4*)(o_ws + (size_t)(base + hh * S) * D + d8 * 8);
        float wh = w[hh] * inv;
        unsigned int ws_[4] = {pk.x, pk.y, pk.z, pk.w};
        #pragma unroll
        for (int e = 0; e < 4; ++e) {
            float lo = __uint_as_float(ws_[e] << 16);
            float hi = __uint_as_float(ws_[e] & 0xffff0000u);
            accv[2*e]   += wh * lo;
            accv[2*e+1] += wh * hi;
        }
    }
    float4* op = (float4*)(out + (size_t)token * D + d8 * 8);
    op[0] = make_float4(accv[0], accv[1], accv[2], accv[3]);
    op[1] = make_float4(accv[4], accv[5], accv[6], accv[7]);
}

// ---------------------------------------------------------------------------
extern "C" void kernel_launch(void* const* d_in, const int* in_sizes, int n_in,
                              void* d_out, int out_size, void* d_ws, size_t ws_size,
                              hipStream_t stream) {
    const float* qk  = (const float*)d_in[0];
    const float* v   = (const float*)d_in[1];
    const float* rot = (const float*)d_in[2];

    float* out         = (float*)d_out;
    float* out_buckets = out + (size_t)B * S * D;

    int*   bucket_ws = (int*)d_ws;                              // 524288 ints
    int*   st_ws     = bucket_ws + (size_t)B * NH * S;          // 524288 ints
    float* logits_ws = (float*)(st_ws + (size_t)B * NH * S);    // 524288 f32
    __hip_bfloat16* o_ws = (__hip_bfloat16*)(logits_ws + (size_t)B * NH * S); // 64 MB
    int*   flag_cnt  = (int*)(o_ws + (size_t)B * NH * S * D);   // 1 int
    int*   flag_list = flag_cnt + 16;                           // <= 524288 ints

    hipMemsetAsync(flag_cnt, 0, sizeof(int), stream);
    hash_kernel<<<B * 32, 256, 0, stream>>>(qk, rot, out_buckets, bucket_ws,
                                            flag_cnt, flag_list);
    hash_fixup_kernel<<<256, 256, 0, stream>>>(qk, rot, flag_cnt, flag_list,
                                               out_buckets, bucket_ws);
    sort_kernel<<<B * NH, 256, 0, stream>>>(bucket_ws, st_ws);
    attn_kernel<<<B * CHUNKS, 256, 0, stream>>>(qk, v, st_ws, o_ws, logits_ws);
    combine_kernel<<<(B * S * 8) / 256, 256, 0, stream>>>(o_ws, logits_ws, out);
}

// Round 9
// 230.624 us; speedup vs baseline: 1.7683x; 1.7683x over previous
//
#include <hip/hip_runtime.h>
#include <hip/hip_bf16.h>
#include <math.h>

// Problem constants
#define B 16
#define S 4096
#define D 64
#define NH 8
#define NBUCK 64          // buckets per hash
#define CHUNKS 512        // chunks per batch (NH * NBUCK)
#define BS 64             // bucket/chunk size

#define GAP_MFMA 0.12f    // flag threshold: bf16-R rounding err sigma~0.013 -> 9 sigma

typedef __attribute__((ext_vector_type(8))) short s8_t;   // 8 bf16 (4 VGPRs)
typedef __attribute__((ext_vector_type(4))) float f4_t;   // MFMA C/D

__device__ inline unsigned short bf16_rne(float x) {
    unsigned int u = __float_as_uint(x);
    u += 0x7fffu + ((u >> 16) & 1u);
    return (unsigned short)(u >> 16);
}
__device__ inline unsigned int pack_bf16_pair(float x0, float x1) {
    return (unsigned int)bf16_rne(x0) | ((unsigned int)bf16_rne(x1) << 16);
}
__device__ inline void split_bf16(float x, unsigned short& h, unsigned short& l) {
    h = bf16_rne(x);
    float hf = __uint_as_float(((unsigned int)h) << 16);
    l = bf16_rne(x - hf);
}
// truncation-pack two f32 into (bf16(x0) | bf16(x1)<<16): one v_perm_b32
__device__ inline unsigned int pack_trunc(float x0, float x1) {
    return __builtin_amdgcn_perm(__float_as_uint(x1), __float_as_uint(x0),
                                 0x07060302u);
}
__device__ inline unsigned short bf16_trunc(float x) {
    return (unsigned short)(__float_as_uint(x) >> 16);
}

// ---------------------------------------------------------------------------
// Kernel 1: MFMA hash (GEMM form). A[m=256 outputs (8h x 32i)][k=64] = R bf16,
// B[k=64][n=128 tokens] = qk split hi/lo (2 MFMAs each). Per odd m-tile,
// finalize per-h top-2 of signed candidates [v,-v] via quad butterfly.
// Ambiguous tokens (gap < GAP_MFMA) get flag byte = 1 (NO global atomics --
// R8's contended flag_cnt atomic inside this loop was a 150 us stall).
// ---------------------------------------------------------------------------
#define HA_OFF 0          // A (R) : 256 rows x 144 B
#define HQH_OFF 36864     // Q hi  : 128 rows x 144 B
#define HQL_OFF 55296     // Q lo  : 128 rows x 144 B
#define HLDS_TOT 73728
#define HSTR 144          // row stride bytes (64 bf16 + 8 pad)

__global__ __launch_bounds__(256, 2) void hash_kernel(
    const float* __restrict__ qk, const float* __restrict__ rot,
    float* __restrict__ out_buckets, int* __restrict__ bucket_ws,
    unsigned char* __restrict__ flag_ws)
{
    __shared__ char lds[HLDS_TOT];
    int tid = threadIdx.x;
    int b    = blockIdx.x >> 5;
    int tile = blockIdx.x & 31;
    int token0 = tile * 128;

    // ---- stage A = R_all: A[m][f] = rot[f*256 + m], bf16 RNE ----
    {
        char* arow = lds + HA_OFF + tid * HSTR;
        #pragma unroll 4
        for (int f = 0; f < 64; f += 2) {
            float r0 = rot[(size_t)f * 256 + tid];
            float r1 = rot[(size_t)(f + 1) * 256 + tid];
            *(unsigned int*)(arow + f * 2) = pack_bf16_pair(r0, r1);
        }
    }
    // ---- stage B = qk tile, split hi/lo ----
    {
        int r = tid >> 1, half = tid & 1;
        int tok = token0 + r;
        const float4* qs = (const float4*)(qk + ((size_t)b * S + tok) * D) + half * 8;
        float xq[32];
        #pragma unroll
        for (int e4 = 0; e4 < 8; ++e4) {
            float4 a = qs[e4];
            xq[e4*4+0]=a.x; xq[e4*4+1]=a.y; xq[e4*4+2]=a.z; xq[e4*4+3]=a.w;
        }
        unsigned int ph[16], pl[16];
        #pragma unroll
        for (int e = 0; e < 16; ++e) {
            unsigned short h0,l0,h1,l1;
            split_bf16(xq[2*e],   h0, l0);
            split_bf16(xq[2*e+1], h1, l1);
            ph[e] = (unsigned int)h0 | ((unsigned int)h1 << 16);
            pl[e] = (unsigned int)l0 | ((unsigned int)l1 << 16);
        }
        char* qh = lds + HQH_OFF + r * HSTR + half * 64;
        char* ql = lds + HQL_OFF + r * HSTR + half * 64;
        #pragma unroll
        for (int e4 = 0; e4 < 4; ++e4) {
            *(uint4*)(qh + e4*16) = make_uint4(ph[e4*4], ph[e4*4+1], ph[e4*4+2], ph[e4*4+3]);
            *(uint4*)(ql + e4*16) = make_uint4(pl[e4*4], pl[e4*4+1], pl[e4*4+2], pl[e4*4+3]);
        }
    }
    __syncthreads();

    int wv   = tid >> 6;
    int lane = tid & 63;
    int quad = lane >> 4;
    int cc   = lane & 15;

    for (int nt = 0; nt < 2; ++nt) {
        int ntg = wv * 2 + nt;            // 0..7 (16-token groups)
        const char* qrh = lds + HQH_OFF + (ntg * 16 + cc) * HSTR + quad * 16;
        const char* qrl = lds + HQL_OFF + (ntg * 16 + cc) * HSTR + quad * 16;
        s8_t bh0 = *(const s8_t*)(qrh);
        s8_t bh1 = *(const s8_t*)(qrh + 64);
        s8_t bl0 = *(const s8_t*)(qrl);
        s8_t bl1 = *(const s8_t*)(qrl + 64);

        float v1 = -3e38f, v2 = -3e38f;
        int i1 = 0;

        for (int mt = 0; mt < 16; ++mt) {
            const char* arow = lds + HA_OFF + (mt * 16 + cc) * HSTR + quad * 16;
            s8_t a0 = *(const s8_t*)(arow);
            s8_t a1 = *(const s8_t*)(arow + 64);
            f4_t acc = (f4_t){0.f, 0.f, 0.f, 0.f};
            acc = __builtin_amdgcn_mfma_f32_16x16x32_bf16(a0, bh0, acc, 0, 0, 0);
            acc = __builtin_amdgcn_mfma_f32_16x16x32_bf16(a1, bh1, acc, 0, 0, 0);
            acc = __builtin_amdgcn_mfma_f32_16x16x32_bf16(a0, bl0, acc, 0, 0, 0);
            acc = __builtin_amdgcn_mfma_f32_16x16x32_bf16(a1, bl1, acc, 0, 0, 0);

            if ((mt & 1) == 0) { v1 = -3e38f; v2 = -3e38f; i1 = 0; }
            int ibase = ((mt & 1) << 4) + (quad << 2);
            #pragma unroll
            for (int r = 0; r < 4; ++r) {
                float vp = acc[r];
                int ip = ibase + r;
                v2 = fmaxf(v2, fminf(vp, v1));
                if (vp > v1) { v1 = vp; i1 = ip; }
                float vn = -vp;
                v2 = fmaxf(v2, fminf(vn, v1));
                if (vn > v1) { v1 = vn; i1 = ip + 32; }
            }

            if (mt & 1) {
                // butterfly merge across the 4 quads (lane bits 4,5)
                #pragma unroll
                for (int off = 16; off <= 32; off <<= 1) {
                    float ov1 = __shfl_xor(v1, off, 64);
                    float ov2 = __shfl_xor(v2, off, 64);
                    int   oi1 = __shfl_xor(i1, off, 64);
                    float nv2 = fmaxf(fmaxf(v2, ov2), fminf(v1, ov1));
                    if (ov1 > v1) { v1 = ov1; i1 = oi1; }
                    v2 = nv2;
                }
                if (quad == 0) {
                    int h = mt >> 1;
                    int tok = token0 + ntg * 16 + cc;
                    size_t idx = (size_t)(b * NH + h) * S + tok;
                    bucket_ws[idx] = i1;
                    out_buckets[idx] = (float)(i1 + h * NBUCK);
                    flag_ws[idx] = (v1 - v2 < GAP_MFMA) ? 1 : 0;  // fire-and-forget
                }
            }
        }
    }
}

// ---------------------------------------------------------------------------
// Kernel 1b: exact f64 recompute for flagged tokens. Block-local compaction
// (LDS counter, zero global atomics) over 2048-token tiles, then the
// compacted list is processed densely (no wave-divergence waste).
// Decision-equivalent to a full-f64 hash (first-occurrence ties).
// ---------------------------------------------------------------------------
__global__ __launch_bounds__(256) void hash_fixup_kernel(
    const float* __restrict__ qk, const float* __restrict__ rot,
    const unsigned char* __restrict__ flag_ws,
    float* __restrict__ out_buckets, int* __restrict__ bucket_ws)
{
    __shared__ int list[2048];
    __shared__ int cnt;
    int tid = threadIdx.x;
    if (tid == 0) cnt = 0;
    __syncthreads();

    int base = blockIdx.x * 2048;
    for (int i = tid; i < 2048; i += 256) {
        if (flag_ws[base + i]) {
            int slot = atomicAdd(&cnt, 1);    // LDS atomic (block-local)
            list[slot] = base + i;
        }
    }
    __syncthreads();
    int n = cnt;

    for (int j = tid; j < n; j += 256) {
        int gid = list[j];
        int bh = gid >> 12, t = gid & (S - 1);
        int b = bh >> 3, h = bh & 7;
        const float* row = qk + ((size_t)b * S + t) * D;

        double acc[32];
        #pragma unroll
        for (int i = 0; i < 32; ++i) acc[i] = 0.0;
        for (int f = 0; f < 64; ++f) {
            double x = (double)row[f];
            const float* rr = rot + f * (NH * 32) + h * 32;
            #pragma unroll
            for (int i = 0; i < 32; ++i)
                acc[i] = __fma_rn(x, (double)rr[i], acc[i]);
        }
        double best = acc[0]; int bi = 0;
        double worst = acc[0]; int wi = 0;
        #pragma unroll
        for (int i = 1; i < 32; ++i) {
            if (acc[i] > best)  { best = acc[i]; bi = i; }
            if (acc[i] < worst) { worst = acc[i]; wi = i; }
        }
        int bucket = (-worst > best) ? (32 + wi) : bi;
        bucket_ws[gid] = bucket;
        out_buckets[gid] = (float)(bucket + h * NBUCK);
    }
}

// ---------------------------------------------------------------------------
// Kernel 2: parallel stable counting sort per (b,h). 256 threads (4 waves).
// ---------------------------------------------------------------------------
__global__ __launch_bounds__(256) void sort_kernel(
    const int* __restrict__ bucket_ws, int* __restrict__ st_ws)
{
    __shared__ int sb[S];
    __shared__ int hist[4][64];
    __shared__ int bpref[64];
    __shared__ int woff[4][64];

    int tid  = threadIdx.x;
    int wv   = tid >> 6;
    int lane = tid & 63;
    int base = blockIdx.x * S;

    hist[wv][lane] = 0;
    __syncthreads();

    int qbase = wv * 1024;
    #pragma unroll
    for (int i = 0; i < 16; ++i) {
        int t = qbase + i * 64 + lane;
        int v = bucket_ws[base + t];
        sb[t] = v;
        atomicAdd(&hist[wv][v], 1);
    }
    __syncthreads();

    if (wv == 0) {
        int total = hist[0][lane] + hist[1][lane] + hist[2][lane] + hist[3][lane];
        int x = total;
        #pragma unroll
        for (int off = 1; off < 64; off <<= 1) {
            int y = __shfl_up(x, off, 64);
            if (lane >= off) x += y;
        }
        bpref[lane] = x - total;
    }
    __syncthreads();
    {
        int o = bpref[lane];
        for (int w2 = 0; w2 < 4; ++w2) {
            if (w2 < wv) o += hist[w2][lane];
        }
        woff[wv][lane] = o;
    }
    __syncthreads();

    for (int g = 0; g < 16; ++g) {
        int t = qbase + g * 64 + lane;
        int v = sb[t];

        unsigned long long m = ~0ULL;
        #pragma unroll
        for (int bit = 0; bit < 6; ++bit) {
            unsigned long long bm = __ballot((v >> bit) & 1);
            m &= ((v >> bit) & 1) ? bm : ~bm;
        }
        unsigned long long below = (lane == 63) ? ~0ULL >> 1
                                 : ((1ULL << lane) - 1ULL);
        int rank = __popcll(m & below);
        int cnt  = __popcll(m);

        int pos = woff[wv][v] + rank;
        st_ws[base + pos] = t;

        if ((m & below) == 0ULL)
            woff[wv][v] += cnt;
        __builtin_amdgcn_s_waitcnt(0);
    }
}

// ---------------------------------------------------------------------------
// Kernel 3: per-chunk attention, plain-bf16 MFMA, truncation-packed converts.
// LDS layout (37888 B -> 4 blocks/CU):
//   K  [128 rows][144 B] @0      (18432)  normalized keys bf16
//                                 -- rows 0..63 overlaid by P[64][144B] post-dots
//   VtP[64 rows][288 B]  @18432  (18432)  V^T packed: dword = keys(2a,2a+1)
//   nrm @36864 (512), tkx @37376 (512)
// ---------------------------------------------------------------------------
#define OFF_VT 18432
#define OFF_NRM 36864
#define OFF_TKX 37376
#define LDS_TOT 37888
#define KSTRB 144     // K/P row stride bytes (72 bf16), 16B-aligned
#define VSTRD 72      // VtP row stride in dwords (288 B)

__global__ __launch_bounds__(256, 4) void attn_kernel(
    const float* __restrict__ qk, const float* __restrict__ v,
    const int* __restrict__ st_ws,
    __hip_bfloat16* __restrict__ o_ws, float* __restrict__ logits_ws)
{
    __shared__ char lds[LDS_TOT];
    float* nrm_s = (float*)(lds + OFF_NRM);
    int*   tkx   = (int*)(lds + OFF_TKX);
    unsigned int* VtP = (unsigned int*)(lds + OFF_VT);

    int tid = threadIdx.x;
    int c = blockIdx.x & (CHUNKS - 1);
    int b = blockIdx.x >> 9;
    int h = c >> 6;
    int sbase = b * (NH * S);

    if (tid < 128) {
        int cc2 = (tid < 64) ? c : ((c + CHUNKS - 1) & (CHUNKS - 1));
        tkx[tid] = st_ws[sbase + cc2 * BS + (tid & 63)];
    }
    __syncthreads();

    // ---- stage K (normalized bf16, row-major) ----
    {
        int r = tid >> 1, half = tid & 1;
        int tok = tkx[r];
        const float4* qs = (const float4*)(qk + ((size_t)b * S + tok) * D) + half * 8;
        float xq[32];
        #pragma unroll
        for (int e4 = 0; e4 < 8; ++e4) {
            float4 a = qs[e4];
            xq[e4*4+0]=a.x; xq[e4*4+1]=a.y; xq[e4*4+2]=a.z; xq[e4*4+3]=a.w;
        }
        float ss = 0.f;
        #pragma unroll
        for (int e = 0; e < 32; ++e) ss += xq[e]*xq[e];
        ss += __shfl_xor(ss, 1);
        float nr = sqrtf(ss);
        float inv = 1.0f / fmaxf(nr, 1e-12f);
        if (!half) nrm_s[r] = nr;

        unsigned int pk[16];
        #pragma unroll
        for (int e = 0; e < 16; ++e)
            pk[e] = pack_trunc(xq[2*e] * inv, xq[2*e+1] * inv);
        char* kb = lds + r * KSTRB + half * 64;
        #pragma unroll
        for (int e4 = 0; e4 < 4; ++e4)
            *(uint4*)(kb + e4*16) = make_uint4(pk[e4*4], pk[e4*4+1], pk[e4*4+2], pk[e4*4+3]);
    }
    // ---- stage V^T packed (dword = 2 consecutive keys) ----
    {
        int a = tid & 63, sub = tid >> 6;     // a = key pair, sub = dim quarter
        int tok0 = tkx[2*a], tok1 = tkx[2*a+1];
        const float4* v0 = (const float4*)(v + ((size_t)b * S + tok0) * D + sub * 16);
        const float4* v1 = (const float4*)(v + ((size_t)b * S + tok1) * D + sub * 16);
        float x0[16], x1[16];
        #pragma unroll
        for (int e4 = 0; e4 < 4; ++e4) {
            float4 p0 = v0[e4], p1 = v1[e4];
            x0[e4*4+0]=p0.x; x0[e4*4+1]=p0.y; x0[e4*4+2]=p0.z; x0[e4*4+3]=p0.w;
            x1[e4*4+0]=p1.x; x1[e4*4+1]=p1.y; x1[e4*4+2]=p1.z; x1[e4*4+3]=p1.w;
        }
        #pragma unroll
        for (int e = 0; e < 16; ++e) {
            int dd = sub * 16 + e;
            VtP[dd * VSTRD + a] = pack_trunc(x0[e], x1[e]);
        }
    }
    __syncthreads();

    int wv   = tid >> 6;
    int lane = tid & 63;
    int quad = lane >> 4;
    int cc   = lane & 15;

    // ---- dots: QK^T via bf16 MFMA ----
    int qrow = wv * 16 + cc;
    f4_t acc[8];
    #pragma unroll
    for (int t = 0; t < 8; ++t) acc[t] = (f4_t){0.f,0.f,0.f,0.f};

    #pragma unroll
    for (int kc = 0; kc < 2; ++kc) {
        int aoff = kc * 64 + quad * 16;
        s8_t av = *(const s8_t*)(lds + qrow * KSTRB + aoff);
        #pragma unroll
        for (int t = 0; t < 8; ++t) {
            s8_t bv = *(const s8_t*)(lds + (t * 16 + cc) * KSTRB + aoff);
            acc[t] = __builtin_amdgcn_mfma_f32_16x16x32_bf16(av, bv, acc[t], 0, 0, 0);
        }
    }

    // ---- scale + self-mask + softmax ----
    int tqi[4];
    float sc[4];
    #pragma unroll
    for (int g = 0; g < 4; ++g) {
        int q = wv * 16 + quad * 4 + g;
        tqi[g] = tkx[q];
        sc[g] = nrm_s[q] * 0.125f;
    }
    int tki[8];
    #pragma unroll
    for (int t = 0; t < 8; ++t) tki[t] = tkx[t * 16 + cc];

    #pragma unroll
    for (int t = 0; t < 8; ++t)
        #pragma unroll
        for (int g = 0; g < 4; ++g) {
            float d = acc[t][g] * sc[g];
            if (tqi[g] == tki[t]) d = -1e5f;
            acc[t][g] = d;
        }

    float mx[4];
    #pragma unroll
    for (int g = 0; g < 4; ++g) {
        float m = acc[0][g];
        #pragma unroll
        for (int t = 1; t < 8; ++t) m = fmaxf(m, acc[t][g]);
        mx[g] = m;
    }
    #pragma unroll
    for (int msk = 1; msk <= 8; msk <<= 1)
        #pragma unroll
        for (int g = 0; g < 4; ++g) mx[g] = fmaxf(mx[g], __shfl_xor(mx[g], msk, 64));

    float sm[4] = {0.f, 0.f, 0.f, 0.f};
    #pragma unroll
    for (int t = 0; t < 8; ++t)
        #pragma unroll
        for (int g = 0; g < 4; ++g) {
            float p = __expf(acc[t][g] - mx[g]);
            acc[t][g] = p;
            sm[g] += p;
        }
    #pragma unroll
    for (int msk = 1; msk <= 8; msk <<= 1)
        #pragma unroll
        for (int g = 0; g < 4; ++g) sm[g] += __shfl_xor(sm[g], msk, 64);

    float pinv[4];
    #pragma unroll
    for (int g = 0; g < 4; ++g) pinv[g] = 1.0f / sm[g];

    if (cc == 0) {
        #pragma unroll
        for (int g = 0; g < 4; ++g)
            logits_ws[sbase + h * S + tqi[g]] = mx[g] + __logf(sm[g]);
    }

    // ---- P -> bf16 into LDS, overlaying K rows 0..63 ----
    __syncthreads();
    #pragma unroll
    for (int t = 0; t < 8; ++t) {
        int key = t * 16 + cc;
        #pragma unroll
        for (int g = 0; g < 4; ++g) {
            int q = wv * 16 + quad * 4 + g;
            *(unsigned short*)(lds + q * KSTRB + key * 2) =
                bf16_trunc(acc[t][g] * pinv[g]);
        }
    }

    // ---- PV via bf16 MFMA (A = own wave's P rows, B = VtP rows) ----
    f4_t oacc[4];
    #pragma unroll
    for (int n = 0; n < 4; ++n) oacc[n] = (f4_t){0.f,0.f,0.f,0.f};

    #pragma unroll
    for (int kc = 0; kc < 4; ++kc) {
        int koff = kc * 64 + quad * 16;   // byte offset: key k at byte 2k
        s8_t pa = *(const s8_t*)(lds + (wv * 16 + cc) * KSTRB + koff);
        #pragma unroll
        for (int n = 0; n < 4; ++n) {
            s8_t bv = *(const s8_t*)((const char*)(VtP + (n * 16 + cc) * VSTRD) + koff);
            oacc[n] = __builtin_amdgcn_mfma_f32_16x16x32_bf16(pa, bv, oacc[n], 0, 0, 0);
        }
    }

    // ---- write O (bf16, truncation) ----
    #pragma unroll
    for (int g = 0; g < 4; ++g) {
        __hip_bfloat16* op = o_ws + ((size_t)(sbase + h * S + tqi[g])) * D;
        #pragma unroll
        for (int n = 0; n < 4; ++n)
            *(unsigned short*)(op + n * 16 + cc) = bf16_trunc(oacc[n][g]);
    }
}

// ---------------------------------------------------------------------------
// Kernel 4: combine hash rounds with softmax(logits) weights. o_ws is bf16.
// ---------------------------------------------------------------------------
__global__ __launch_bounds__(256) void combine_kernel(
    const __hip_bfloat16* __restrict__ o_ws, const float* __restrict__ logits_ws,
    float* __restrict__ out)
{
    int gid = blockIdx.x * 256 + threadIdx.x;
    int token = gid >> 3;          // b*S + t
    int d8 = gid & 7;
    int b = token >> 12;
    int t = token & (S - 1);
    int base = b * (NH * S) + t;

    float l[8];
    #pragma unroll
    for (int hh = 0; hh < 8; ++hh) l[hh] = logits_ws[base + hh * S];
    float m = l[0];
    #pragma unroll
    for (int hh = 1; hh < 8; ++hh) m = fmaxf(m, l[hh]);
    float w[8]; float ssum = 0.f;
    #pragma unroll
    for (int hh = 0; hh < 8; ++hh) { w[hh] = __expf(l[hh] - m); ssum += w[hh]; }
    float inv = 1.0f / ssum;

    float accv[8] = {0,0,0,0,0,0,0,0};
    #pragma unroll
    for (int hh = 0; hh < 8; ++hh) {
        uint4 pk = *(const uint4*)(o_ws + (size_t)(base + hh * S) * D + d8 * 8);
        float wh = w[hh] * inv;
        unsigned int ws_[4] = {pk.x, pk.y, pk.z, pk.w};
        #pragma unroll
        for (int e = 0; e < 4; ++e) {
            float lo = __uint_as_float(ws_[e] << 16);
            float hi = __uint_as_float(ws_[e] & 0xffff0000u);
            accv[2*e]   += wh * lo;
            accv[2*e+1] += wh * hi;
        }
    }
    float4* op = (float4*)(out + (size_t)token * D + d8 * 8);
    op[0] = make_float4(accv[0], accv[1], accv[2], accv[3]);
    op[1] = make_float4(accv[4], accv[5], accv[6], accv[7]);
}

// ---------------------------------------------------------------------------
extern "C" void kernel_launch(void* const* d_in, const int* in_sizes, int n_in,
                              void* d_out, int out_size, void* d_ws, size_t ws_size,
                              hipStream_t stream) {
    const float* qk  = (const float*)d_in[0];
    const float* v   = (const float*)d_in[1];
    const float* rot = (const float*)d_in[2];

    float* out         = (float*)d_out;
    float* out_buckets = out + (size_t)B * S * D;

    int*   bucket_ws = (int*)d_ws;                              // 524288 ints
    int*   st_ws     = bucket_ws + (size_t)B * NH * S;          // 524288 ints
    float* logits_ws = (float*)(st_ws + (size_t)B * NH * S);    // 524288 f32
    __hip_bfloat16* o_ws = (__hip_bfloat16*)(logits_ws + (size_t)B * NH * S); // 64 MB
    unsigned char* flag_ws = (unsigned char*)(o_ws + (size_t)B * NH * S * D); // 512 KB

    hash_kernel<<<B * 32, 256, 0, stream>>>(qk, rot, out_buckets, bucket_ws,
                                            flag_ws);
    hash_fixup_kernel<<<(B * NH * S) / 2048, 256, 0, stream>>>(
        qk, rot, flag_ws, out_buckets, bucket_ws);
    sort_kernel<<<B * NH, 256, 0, stream>>>(bucket_ws, st_ws);
    attn_kernel<<<B * CHUNKS, 256, 0, stream>>>(qk, v, st_ws, o_ws, logits_ws);
    combine_kernel<<<(B * S * 8) / 256, 256, 0, stream>>>(o_ws, logits_ws, out);
}